// Round 12
// baseline (94619.122 us; speedup 1.0000x reference)
//
#include <hip/hip_runtime.h>
#include <math.h>

// Problem sizes (fixed)
#define T_STEPS 32768
#define DIM 512
#define HID 1024
#define SD 256            // state dim S

// 256 persistent WGs (1/CU), 128 threads = 2 independent waves, 2 units/wave.
#define NWG 256
#define RBT 128

// Poll-alignment grid in s_memrealtime ticks (REFCLK ~100 MHz):
// 48 ticks = 480 ns = ~1152 core cyc @2.4GHz >= poll RT + check.
#define GRID_TICKS 48u

typedef unsigned u32x4 __attribute__((ext_vector_type(4)));
typedef float    f32x2 __attribute__((ext_vector_type(2)));

// Pin loaded weights into registers: opaque def prevents per-step re-fetch.
#define PIN2(v) asm volatile("" : "+v"((v).x), "+v"((v).y))

__device__ __forceinline__ float sigmoid_fast(float x) {
    float e = __builtin_amdgcn_exp2f(-1.4426950408889634f * x);
    return __builtin_amdgcn_rcpf(1.f + e);
}
__device__ __forceinline__ float tanh_fast(float x) {
    float e = __builtin_amdgcn_exp2f(2.8853900817779268f * x);   // exp(2x)
    return 1.f - 2.f * __builtin_amdgcn_rcpf(e + 1.f);
}
__device__ __forceinline__ float softplus_f(float x) {
    float ax = fabsf(x);
    return fmaxf(x, 0.f) + log1pf(expf(-ax));
}

// Exact 64-lane sum: 4 DPP stages (xor1,2,7,8) + 2 shfl stages (xor16, xor32).
__device__ __forceinline__ float wave_sum(float v) {
    int x;
    x = __builtin_amdgcn_mov_dpp(__float_as_int(v), 0xB1,  0xf, 0xf, true); v += __int_as_float(x);
    x = __builtin_amdgcn_mov_dpp(__float_as_int(v), 0x4E,  0xf, 0xf, true); v += __int_as_float(x);
    x = __builtin_amdgcn_mov_dpp(__float_as_int(v), 0x141, 0xf, 0xf, true); v += __int_as_float(x);
    x = __builtin_amdgcn_mov_dpp(__float_as_int(v), 0x128, 0xf, 0xf, true); v += __int_as_float(x);
    v += __shfl_xor(v, 16, 64);
    v += __shfl_xor(v, 32, 64);
    return v;
}

// ---------------------------------------------------------------------------
// h state: u32/elem, low 2 bits = step tag (t&3). Buffers by step parity.
// init runs every call (replay-safe; scrubs stale tags).
// ---------------------------------------------------------------------------
__global__ void init_kernel(const float* __restrict__ h0,
                            unsigned* __restrict__ htag) {
    int i = blockIdx.x * 256 + threadIdx.x;      // grid 4 x 256 = 1024
    unsigned v = __float_as_uint(tanhf(h0[i]));
    htag[i]       = v & ~3u;   // h_0, tag 0
    htag[HID + i] = 0u;        // buffer1 scrub (readers expect odd tags)
}

#define TAGCHK(m, tg)                                                          \
    m = ((q0.x ^ tg) | (q0.y ^ tg)) | ((q0.z ^ tg) | (q0.w ^ tg))              \
      | ((q1.x ^ tg) | (q1.y ^ tg)) | ((q1.z ^ tg) | (q1.w ^ tg))              \
      | ((q2.x ^ tg) | (q2.y ^ tg)) | ((q2.z ^ tg) | (q2.w ^ tg))              \
      | ((q3.x ^ tg) | (q3.y ^ tg)) | ((q3.z ^ tg) | (q3.w ^ tg))

// ---------------------------------------------------------------------------
// persistent fused scan, wave-granular (no LDS, no barriers). Protocol
// byte-equivalent to round 11 (proven, 48.2 ms): 1-deep spin with fused
// y-prefetch, all loads retired inside each asm block, register-only tail.
// ONE change: re-samples in the miss loop are aligned to a global
// s_memrealtime grid, so all waves' detecting samples land on the same
// instant -> poll-phase spread (the E[max over 512 waves] ~ RT term)
// collapses to a shared residual. Timing-only; correctness untouched.
// ---------------------------------------------------------------------------
__global__ __launch_bounds__(RBT, 1) void gru_scan(
    const float* __restrict__ y, const float* __restrict__ h0,
    const float* __restrict__ w_ih, const float* __restrict__ w_hh,
    const float* __restrict__ b, const float* __restrict__ bn,
    const float* __restrict__ w_out, const float* __restrict__ b_out,
    float* __restrict__ out, unsigned* __restrict__ htag /* [2][HID] */) {
    const int tid  = threadIdx.x;
    const int wg   = blockIdx.x;
    const int wv   = tid >> 6;          // wave 0..1
    const int lane = tid & 63;
    const int half = lane >> 5;         // 0: unit u0, 1: unit u0+1
    const int u0   = wg * 4 + wv * 2;
    const int um   = u0 + half;         // unit this half-wave finalizes

    // hidden weights: 16 elems/lane at 16*lane, as 8 f32x2 per (gate,unit)
    f32x2 wh[3][2][8];
    #pragma unroll
    for (int g = 0; g < 3; ++g)
        #pragma unroll
        for (int uu = 0; uu < 2; ++uu) {
            const f32x2* row = (const f32x2*)&w_hh[(size_t)(g * HID + u0 + uu) * HID + 16 * lane];
            #pragma unroll
            for (int q = 0; q < 8; ++q) { wh[g][uu][q] = row[q]; PIN2(wh[g][uu][q]); }
        }
    // input weights: 8 elems/lane at 8*lane, as 4 f32x2 per (gate,unit)
    f32x2 wi[3][2][4];
    #pragma unroll
    for (int g = 0; g < 3; ++g)
        #pragma unroll
        for (int uu = 0; uu < 2; ++uu) {
            const f32x2* row = (const f32x2*)&w_ih[(size_t)(g * HID + u0 + uu) * DIM + 8 * lane];
            #pragma unroll
            for (int q = 0; q < 4; ++q) { wi[g][uu][q] = row[q]; PIN2(wi[g][uu][q]); }
        }
    // output weights: col c = 2*wg + wv, 16 elems/lane as 8 f32x2
    const int c = 2 * wg + wv;
    f32x2 wo[8];
    #pragma unroll
    for (int q = 0; q < 8; ++q) {
        wo[q] = ((const f32x2*)&w_out[(size_t)c * HID + 16 * lane])[q];
        PIN2(wo[q]);
    }

    const float bi_r = b[um], bi_z = b[HID + um], bi_n = b[2 * HID + um];
    const float bnu  = bn[um];
    const float bo   = b_out[c];

    float hp = tanhf(h0[um]);           // own unit's h, fp32 in-register

    // y-side pre-reduced gate inputs (+bias) for step t (t=0 in prologue)
    float yr, yz, yi;
    {
        const f32x2* yv = (const f32x2*)&y[8 * lane];
        f32x2 acc[6] = {};
        #pragma unroll
        for (int g = 0; g < 3; ++g)
            #pragma unroll
            for (int uu = 0; uu < 2; ++uu)
                #pragma unroll
                for (int q = 0; q < 4; ++q)
                    acc[g*2+uu] = wi[g][uu][q] * yv[q] + acc[g*2+uu];
        float d[6];
        #pragma unroll
        for (int k = 0; k < 6; ++k) d[k] = wave_sum(acc[k].x + acc[k].y);
        yr = (half ? d[1] : d[0]) + bi_r;
        yz = (half ? d[3] : d[2]) + bi_z;
        yi = (half ? d[5] : d[4]) + bi_n;
    }

    const size_t TS = (size_t)T_STEPS * SD;

    for (int t = 0; t <= T_STEPS; ++t) {
        const unsigned tg = (unsigned)t & 3u;
        const unsigned* pa = htag + (size_t)((t & 1) * HID + 16 * lane);
        const int tn = (t + 1 < T_STEPS) ? (t + 1) : 0;       // OOB clamp
        const float* ya = &y[(size_t)tn * DIM + 8 * lane];

        // ---- first sample immediate (fused y prefetch); all loads retired
        // ---- by the internal vmcnt(0). Stragglers detect here instantly.
        u32x4 q0, q1, q2, q3, yq0, yq1;
        asm volatile(
            "global_load_dwordx4 %[y0], %[ya], off\n\t"
            "global_load_dwordx4 %[y1], %[ya], off offset:16\n\t"
            "global_load_dwordx4 %[q0], %[pa], off sc0 sc1\n\t"
            "global_load_dwordx4 %[q1], %[pa], off offset:16 sc0 sc1\n\t"
            "global_load_dwordx4 %[q2], %[pa], off offset:32 sc0 sc1\n\t"
            "global_load_dwordx4 %[q3], %[pa], off offset:48 sc0 sc1\n\t"
            "s_waitcnt vmcnt(0)"
            : [q0]"=&v"(q0), [q1]"=&v"(q1), [q2]"=&v"(q2), [q3]"=&v"(q3),
              [y0]"=&v"(yq0), [y1]"=&v"(yq1)
            : [pa]"v"(pa), [ya]"v"(ya)
            : "memory");
        unsigned m; TAGCHK(m, tg);
        while ((m & 3u) != 0u) {
            // phase-align the re-sample to the global realtime grid: all
            // waves' detecting samples land on the same slot boundary.
            // (s_memrealtime is lgkm-counted; no vmcnt interaction.)
            {
                unsigned rt0 = (unsigned)__builtin_amdgcn_s_memrealtime();
                unsigned tgt = rt0 - (rt0 % GRID_TICKS) + GRID_TICKS;
                while ((int)((unsigned)__builtin_amdgcn_s_memrealtime() - tgt) < 0) {}
            }
            asm volatile(
                "global_load_dwordx4 %[q0], %[pa], off sc0 sc1\n\t"
                "global_load_dwordx4 %[q1], %[pa], off offset:16 sc0 sc1\n\t"
                "global_load_dwordx4 %[q2], %[pa], off offset:32 sc0 sc1\n\t"
                "global_load_dwordx4 %[q3], %[pa], off offset:48 sc0 sc1\n\t"
                "s_waitcnt vmcnt(0)"
                : [q0]"=&v"(q0), [q1]"=&v"(q1), [q2]"=&v"(q2), [q3]"=&v"(q3)
                : [pa]"v"(pa)
                : "memory");
            TAGCHK(m, tg);
        }
        // h values as 8 f32x2 (tag bits in mantissa LSBs: error 2^-21, benign)
        f32x2 hv[8];
        hv[0] = f32x2{__uint_as_float(q0.x), __uint_as_float(q0.y)};
        hv[1] = f32x2{__uint_as_float(q0.z), __uint_as_float(q0.w)};
        hv[2] = f32x2{__uint_as_float(q1.x), __uint_as_float(q1.y)};
        hv[3] = f32x2{__uint_as_float(q1.z), __uint_as_float(q1.w)};
        hv[4] = f32x2{__uint_as_float(q2.x), __uint_as_float(q2.y)};
        hv[5] = f32x2{__uint_as_float(q2.z), __uint_as_float(q2.w)};
        hv[6] = f32x2{__uint_as_float(q3.x), __uint_as_float(q3.y)};
        hv[7] = f32x2{__uint_as_float(q3.z), __uint_as_float(q3.w)};

        // ---- critical path: 48 pk-FMA -> 6 reduces -> gates -> publish ----
        if (t < T_STEPS) {
            f32x2 acc[6] = {};
            #pragma unroll
            for (int g = 0; g < 3; ++g)
                #pragma unroll
                for (int uu = 0; uu < 2; ++uu)
                    #pragma unroll
                    for (int q = 0; q < 8; ++q)
                        acc[g*2+uu] = wh[g][uu][q] * hv[q] + acc[g*2+uu];
            // issue order: r (0,1) and n (4,5) chains first (feed tanh), z last
            float s[6];
            s[0] = wave_sum(acc[0].x + acc[0].y);
            s[1] = wave_sum(acc[1].x + acc[1].y);
            s[4] = wave_sum(acc[4].x + acc[4].y);
            s[5] = wave_sum(acc[5].x + acc[5].y);
            s[2] = wave_sum(acc[2].x + acc[2].y);
            s[3] = wave_sum(acc[3].x + acc[3].y);

            float r = sigmoid_fast((half ? s[1] : s[0]) + yr);
            float z = sigmoid_fast((half ? s[3] : s[2]) + yz);
            float n = tanh_fast(yi + r * ((half ? s[5] : s[4]) + bnu));
            float hnew = n + z * (hp - n);
            hp = hnew;

            if ((lane & 31) == 0) {
                unsigned pv = (__float_as_uint(hnew) & ~3u) | (((unsigned)t + 1u) & 3u);
                unsigned* pp = htag + (size_t)(((t + 1) & 1) * HID + um);
                asm volatile("global_store_dword %0, %1, off sc0 sc1"
                             :: "v"(pp), "v"(pv) : "memory");
            }
            __builtin_amdgcn_sched_barrier(0);   // publish before any tail work
        }

        // ---- tail (registers only; NO vmem-dependent uses -> no waitcnt) ----
        {
            f32x2 yv[4];
            yv[0] = f32x2{__uint_as_float(yq0.x), __uint_as_float(yq0.y)};
            yv[1] = f32x2{__uint_as_float(yq0.z), __uint_as_float(yq0.w)};
            yv[2] = f32x2{__uint_as_float(yq1.x), __uint_as_float(yq1.y)};
            yv[3] = f32x2{__uint_as_float(yq1.z), __uint_as_float(yq1.w)};
            f32x2 acc[6] = {};
            #pragma unroll
            for (int g = 0; g < 3; ++g)
                #pragma unroll
                for (int uu = 0; uu < 2; ++uu)
                    #pragma unroll
                    for (int q = 0; q < 4; ++q)
                        acc[g*2+uu] = wi[g][uu][q] * yv[q] + acc[g*2+uu];
            float d[6];
            #pragma unroll
            for (int k = 0; k < 6; ++k) d[k] = wave_sum(acc[k].x + acc[k].y);
            yr = (half ? d[1] : d[0]) + bi_r;
            yz = (half ? d[3] : d[2]) + bi_z;
            yi = (half ? d[5] : d[4]) + bi_n;
        }

        // out row t-1 from this iteration's polled h (hs[t-1] = h_t), in regs
        if (t > 0) {
            f32x2 acc = {};
            #pragma unroll
            for (int q = 0; q < 8; ++q) acc = wo[q] * hv[q] + acc;
            float p = wave_sum(acc.x + acc.y);
            if (lane == 0) {
                float v = p + bo;
                size_t row = (size_t)(t - 1);
                if (c >= SD) out[TS + row * SD + (c - SD)] = softplus_f(v);
                else         out[row * SD + c] = v;       // fire-and-forget
            }
        }
    }
    asm volatile("s_waitcnt vmcnt(0)" ::: "memory");   // drain stores
}

// ---------------------------------------------------------------------------
extern "C" void kernel_launch(void* const* d_in, const int* in_sizes, int n_in,
                              void* d_out, int out_size, void* d_ws, size_t ws_size,
                              hipStream_t stream) {
    const float* y     = (const float*)d_in[0];
    const float* h0    = (const float*)d_in[1];
    const float* w_ih  = (const float*)d_in[2];
    const float* w_hh  = (const float*)d_in[3];
    const float* b     = (const float*)d_in[4];
    const float* bn    = (const float*)d_in[5];
    const float* w_out = (const float*)d_in[6];
    const float* b_out = (const float*)d_in[7];
    float* out = (float*)d_out;

    unsigned* htag = (unsigned*)d_ws;   // [2][HID] u32 = 8 KB

    hipLaunchKernelGGL(init_kernel, dim3(4), dim3(256), 0, stream, h0, htag);
    hipLaunchKernelGGL(gru_scan, dim3(NWG), dim3(RBT), 0, stream,
                       y, h0, w_ih, w_hh, b, bn, w_out, b_out, out, htag);
}

// Round 13
// 48020.786 us; speedup vs baseline: 1.9704x; 1.9704x over previous
//
#include <hip/hip_runtime.h>
#include <math.h>

// Problem sizes (fixed)
#define T_STEPS 32768
#define DIM 512
#define HID 1024
#define SD 256            // state dim S

// 256 persistent WGs (1/CU), 128 threads = 2 independent waves, 2 units/wave.
#define NWG 256
#define RBT 128

typedef unsigned u32x4 __attribute__((ext_vector_type(4)));
typedef float    f32x2 __attribute__((ext_vector_type(2)));

// Pin loaded weights into registers: opaque def prevents per-step re-fetch.
#define PIN2(v) asm volatile("" : "+v"((v).x), "+v"((v).y))

__device__ __forceinline__ float sigmoid_fast(float x) {
    float e = __builtin_amdgcn_exp2f(-1.4426950408889634f * x);
    return __builtin_amdgcn_rcpf(1.f + e);
}
__device__ __forceinline__ float tanh_fast(float x) {
    float e = __builtin_amdgcn_exp2f(2.8853900817779268f * x);   // exp(2x)
    return 1.f - 2.f * __builtin_amdgcn_rcpf(e + 1.f);
}
__device__ __forceinline__ float softplus_f(float x) {
    float ax = fabsf(x);
    return fmaxf(x, 0.f) + log1pf(expf(-ax));
}

// Exact 64-lane sum: 4 DPP stages (xor1,2,7,8) + 2 shfl stages (xor16, xor32).
__device__ __forceinline__ float wave_sum(float v) {
    int x;
    x = __builtin_amdgcn_mov_dpp(__float_as_int(v), 0xB1,  0xf, 0xf, true); v += __int_as_float(x);
    x = __builtin_amdgcn_mov_dpp(__float_as_int(v), 0x4E,  0xf, 0xf, true); v += __int_as_float(x);
    x = __builtin_amdgcn_mov_dpp(__float_as_int(v), 0x141, 0xf, 0xf, true); v += __int_as_float(x);
    x = __builtin_amdgcn_mov_dpp(__float_as_int(v), 0x128, 0xf, 0xf, true); v += __int_as_float(x);
    v += __shfl_xor(v, 16, 64);
    v += __shfl_xor(v, 32, 64);
    return v;
}

// ---------------------------------------------------------------------------
// h state: u32/elem, low 2 bits = step tag (t&3). Buffers by step parity.
// init runs every call (replay-safe; scrubs stale tags).
// ---------------------------------------------------------------------------
__global__ void init_kernel(const float* __restrict__ h0,
                            unsigned* __restrict__ htag) {
    int i = blockIdx.x * 256 + threadIdx.x;      // grid 4 x 256 = 1024
    unsigned v = __float_as_uint(tanhf(h0[i]));
    htag[i]       = v & ~3u;   // h_0, tag 0
    htag[HID + i] = 0u;        // buffer1 scrub (readers expect odd tags)
}

#define TAGCHK(m, tg)                                                          \
    m = ((q0.x ^ tg) | (q0.y ^ tg)) | ((q0.z ^ tg) | (q0.w ^ tg))              \
      | ((q1.x ^ tg) | (q1.y ^ tg)) | ((q1.z ^ tg) | (q1.w ^ tg))              \
      | ((q2.x ^ tg) | (q2.y ^ tg)) | ((q2.z ^ tg) | (q2.w ^ tg))              \
      | ((q3.x ^ tg) | (q3.y ^ tg)) | ((q3.z ^ tg) | (q3.w ^ tg))

// ---------------------------------------------------------------------------
// persistent fused scan, wave-granular (no LDS, no barriers). Byte-identical
// to round 11 (proven best, 47.9 ms): 1-deep free-running spin with fused
// y-prefetch, all loads retired inside each asm block, register-only tail
// (no vmem-dependent uses -> no compiler vmcnt drain of the publish), and
// f32x2 dot products (v_pk_fma_f32 on the detect->publish serial path).
// ---------------------------------------------------------------------------
__global__ __launch_bounds__(RBT, 1) void gru_scan(
    const float* __restrict__ y, const float* __restrict__ h0,
    const float* __restrict__ w_ih, const float* __restrict__ w_hh,
    const float* __restrict__ b, const float* __restrict__ bn,
    const float* __restrict__ w_out, const float* __restrict__ b_out,
    float* __restrict__ out, unsigned* __restrict__ htag /* [2][HID] */) {
    const int tid  = threadIdx.x;
    const int wg   = blockIdx.x;
    const int wv   = tid >> 6;          // wave 0..1
    const int lane = tid & 63;
    const int half = lane >> 5;         // 0: unit u0, 1: unit u0+1
    const int u0   = wg * 4 + wv * 2;
    const int um   = u0 + half;         // unit this half-wave finalizes

    // hidden weights: 16 elems/lane at 16*lane, as 8 f32x2 per (gate,unit)
    f32x2 wh[3][2][8];
    #pragma unroll
    for (int g = 0; g < 3; ++g)
        #pragma unroll
        for (int uu = 0; uu < 2; ++uu) {
            const f32x2* row = (const f32x2*)&w_hh[(size_t)(g * HID + u0 + uu) * HID + 16 * lane];
            #pragma unroll
            for (int q = 0; q < 8; ++q) { wh[g][uu][q] = row[q]; PIN2(wh[g][uu][q]); }
        }
    // input weights: 8 elems/lane at 8*lane, as 4 f32x2 per (gate,unit)
    f32x2 wi[3][2][4];
    #pragma unroll
    for (int g = 0; g < 3; ++g)
        #pragma unroll
        for (int uu = 0; uu < 2; ++uu) {
            const f32x2* row = (const f32x2*)&w_ih[(size_t)(g * HID + u0 + uu) * DIM + 8 * lane];
            #pragma unroll
            for (int q = 0; q < 4; ++q) { wi[g][uu][q] = row[q]; PIN2(wi[g][uu][q]); }
        }
    // output weights: col c = 2*wg + wv, 16 elems/lane as 8 f32x2
    const int c = 2 * wg + wv;
    f32x2 wo[8];
    #pragma unroll
    for (int q = 0; q < 8; ++q) {
        wo[q] = ((const f32x2*)&w_out[(size_t)c * HID + 16 * lane])[q];
        PIN2(wo[q]);
    }

    const float bi_r = b[um], bi_z = b[HID + um], bi_n = b[2 * HID + um];
    const float bnu  = bn[um];
    const float bo   = b_out[c];

    float hp = tanhf(h0[um]);           // own unit's h, fp32 in-register

    // y-side pre-reduced gate inputs (+bias) for step t (t=0 in prologue)
    float yr, yz, yi;
    {
        const f32x2* yv = (const f32x2*)&y[8 * lane];
        f32x2 acc[6] = {};
        #pragma unroll
        for (int g = 0; g < 3; ++g)
            #pragma unroll
            for (int uu = 0; uu < 2; ++uu)
                #pragma unroll
                for (int q = 0; q < 4; ++q)
                    acc[g*2+uu] = wi[g][uu][q] * yv[q] + acc[g*2+uu];
        float d[6];
        #pragma unroll
        for (int k = 0; k < 6; ++k) d[k] = wave_sum(acc[k].x + acc[k].y);
        yr = (half ? d[1] : d[0]) + bi_r;
        yz = (half ? d[3] : d[2]) + bi_z;
        yi = (half ? d[5] : d[4]) + bi_n;
    }

    const size_t TS = (size_t)T_STEPS * SD;

    for (int t = 0; t <= T_STEPS; ++t) {
        const unsigned tg = (unsigned)t & 3u;
        const unsigned* pa = htag + (size_t)((t & 1) * HID + 16 * lane);
        const int tn = (t + 1 < T_STEPS) ? (t + 1) : 0;       // OOB clamp
        const float* ya = &y[(size_t)tn * DIM + 8 * lane];

        // ---- 1-deep spin, fused y(t+1) prefetch; every load retired by the
        // ---- internal vmcnt(0) (nothing in flight crosses the asm boundary)
        u32x4 q0, q1, q2, q3, yq0, yq1;
        asm volatile(
            "global_load_dwordx4 %[y0], %[ya], off\n\t"
            "global_load_dwordx4 %[y1], %[ya], off offset:16\n\t"
            "global_load_dwordx4 %[q0], %[pa], off sc0 sc1\n\t"
            "global_load_dwordx4 %[q1], %[pa], off offset:16 sc0 sc1\n\t"
            "global_load_dwordx4 %[q2], %[pa], off offset:32 sc0 sc1\n\t"
            "global_load_dwordx4 %[q3], %[pa], off offset:48 sc0 sc1\n\t"
            "s_waitcnt vmcnt(0)"
            : [q0]"=&v"(q0), [q1]"=&v"(q1), [q2]"=&v"(q2), [q3]"=&v"(q3),
              [y0]"=&v"(yq0), [y1]"=&v"(yq1)
            : [pa]"v"(pa), [ya]"v"(ya)
            : "memory");
        unsigned m; TAGCHK(m, tg);
        while ((m & 3u) != 0u) {
            asm volatile(
                "global_load_dwordx4 %[q0], %[pa], off sc0 sc1\n\t"
                "global_load_dwordx4 %[q1], %[pa], off offset:16 sc0 sc1\n\t"
                "global_load_dwordx4 %[q2], %[pa], off offset:32 sc0 sc1\n\t"
                "global_load_dwordx4 %[q3], %[pa], off offset:48 sc0 sc1\n\t"
                "s_waitcnt vmcnt(0)"
                : [q0]"=&v"(q0), [q1]"=&v"(q1), [q2]"=&v"(q2), [q3]"=&v"(q3)
                : [pa]"v"(pa)
                : "memory");
            TAGCHK(m, tg);
        }
        // h values as 8 f32x2 (tag bits in mantissa LSBs: error 2^-21, benign)
        f32x2 hv[8];
        hv[0] = f32x2{__uint_as_float(q0.x), __uint_as_float(q0.y)};
        hv[1] = f32x2{__uint_as_float(q0.z), __uint_as_float(q0.w)};
        hv[2] = f32x2{__uint_as_float(q1.x), __uint_as_float(q1.y)};
        hv[3] = f32x2{__uint_as_float(q1.z), __uint_as_float(q1.w)};
        hv[4] = f32x2{__uint_as_float(q2.x), __uint_as_float(q2.y)};
        hv[5] = f32x2{__uint_as_float(q2.z), __uint_as_float(q2.w)};
        hv[6] = f32x2{__uint_as_float(q3.x), __uint_as_float(q3.y)};
        hv[7] = f32x2{__uint_as_float(q3.z), __uint_as_float(q3.w)};

        // ---- critical path: 48 pk-FMA -> 6 reduces -> gates -> publish ----
        if (t < T_STEPS) {
            f32x2 acc[6] = {};
            #pragma unroll
            for (int g = 0; g < 3; ++g)
                #pragma unroll
                for (int uu = 0; uu < 2; ++uu)
                    #pragma unroll
                    for (int q = 0; q < 8; ++q)
                        acc[g*2+uu] = wh[g][uu][q] * hv[q] + acc[g*2+uu];
            // issue order: r (0,1) and n (4,5) chains first (feed tanh), z last
            float s[6];
            s[0] = wave_sum(acc[0].x + acc[0].y);
            s[1] = wave_sum(acc[1].x + acc[1].y);
            s[4] = wave_sum(acc[4].x + acc[4].y);
            s[5] = wave_sum(acc[5].x + acc[5].y);
            s[2] = wave_sum(acc[2].x + acc[2].y);
            s[3] = wave_sum(acc[3].x + acc[3].y);

            float r = sigmoid_fast((half ? s[1] : s[0]) + yr);
            float z = sigmoid_fast((half ? s[3] : s[2]) + yz);
            float n = tanh_fast(yi + r * ((half ? s[5] : s[4]) + bnu));
            float hnew = n + z * (hp - n);
            hp = hnew;

            if ((lane & 31) == 0) {
                unsigned pv = (__float_as_uint(hnew) & ~3u) | (((unsigned)t + 1u) & 3u);
                unsigned* pp = htag + (size_t)(((t + 1) & 1) * HID + um);
                asm volatile("global_store_dword %0, %1, off sc0 sc1"
                             :: "v"(pp), "v"(pv) : "memory");
            }
            __builtin_amdgcn_sched_barrier(0);   // publish before any tail work
        }

        // ---- tail (registers only; NO vmem-dependent uses -> no waitcnt) ----
        {
            f32x2 yv[4];
            yv[0] = f32x2{__uint_as_float(yq0.x), __uint_as_float(yq0.y)};
            yv[1] = f32x2{__uint_as_float(yq0.z), __uint_as_float(yq0.w)};
            yv[2] = f32x2{__uint_as_float(yq1.x), __uint_as_float(yq1.y)};
            yv[3] = f32x2{__uint_as_float(yq1.z), __uint_as_float(yq1.w)};
            f32x2 acc[6] = {};
            #pragma unroll
            for (int g = 0; g < 3; ++g)
                #pragma unroll
                for (int uu = 0; uu < 2; ++uu)
                    #pragma unroll
                    for (int q = 0; q < 4; ++q)
                        acc[g*2+uu] = wi[g][uu][q] * yv[q] + acc[g*2+uu];
            float d[6];
            #pragma unroll
            for (int k = 0; k < 6; ++k) d[k] = wave_sum(acc[k].x + acc[k].y);
            yr = (half ? d[1] : d[0]) + bi_r;
            yz = (half ? d[3] : d[2]) + bi_z;
            yi = (half ? d[5] : d[4]) + bi_n;
        }

        // out row t-1 from this iteration's polled h (hs[t-1] = h_t), in regs
        if (t > 0) {
            f32x2 acc = {};
            #pragma unroll
            for (int q = 0; q < 8; ++q) acc = wo[q] * hv[q] + acc;
            float p = wave_sum(acc.x + acc.y);
            if (lane == 0) {
                float v = p + bo;
                size_t row = (size_t)(t - 1);
                if (c >= SD) out[TS + row * SD + (c - SD)] = softplus_f(v);
                else         out[row * SD + c] = v;       // fire-and-forget
            }
        }
    }
    asm volatile("s_waitcnt vmcnt(0)" ::: "memory");   // drain stores
}

// ---------------------------------------------------------------------------
extern "C" void kernel_launch(void* const* d_in, const int* in_sizes, int n_in,
                              void* d_out, int out_size, void* d_ws, size_t ws_size,
                              hipStream_t stream) {
    const float* y     = (const float*)d_in[0];
    const float* h0    = (const float*)d_in[1];
    const float* w_ih  = (const float*)d_in[2];
    const float* w_hh  = (const float*)d_in[3];
    const float* b     = (const float*)d_in[4];
    const float* bn    = (const float*)d_in[5];
    const float* w_out = (const float*)d_in[6];
    const float* b_out = (const float*)d_in[7];
    float* out = (float*)d_out;

    unsigned* htag = (unsigned*)d_ws;   // [2][HID] u32 = 8 KB

    hipLaunchKernelGGL(init_kernel, dim3(4), dim3(256), 0, stream, h0, htag);
    hipLaunchKernelGGL(gru_scan, dim3(NWG), dim3(RBT), 0, stream,
                       y, h0, w_ih, w_hh, b, bn, w_out, b_out, out, htag);
}